// Round 3
// baseline (215.080 us; speedup 1.0000x reference)
//
#include <hip/hip_runtime.h>

// LearnedClassVectors: bucketize fp32 volume into 10 HU bins, gather (10,12)
// embedding, re-tile into 4x4x4 patches -> out (B=2, 768, 32, 32, 32) fp32.
//
// R1: block = (b, gd, p-chunk of 4 patch positions) x all gh. For each output
// channel o the block writes 32gh x 32gw = 4 KB CONTIGUOUS (vs 128 B in R0),
// fixing DRAM page-activate overhead on the 201 MB write stream. p-chunks
// partition the voxels, so x is still read exactly once.
// R2: fix compile — __builtin_nontemporal_store needs a native vector type,
// not HIP_vector_type<float,4>; use ext_vector_type(4).

#define NTHREADS 256
#define NBLOCKS 1024  // 2 b * 32 gd * 16 p-chunks

typedef float fx4 __attribute__((ext_vector_type(4)));

__global__ __launch_bounds__(NTHREADS) void lcv_kernel(
    const float* __restrict__ x,
    const float* __restrict__ vectors,
    float* __restrict__ out)
{
    // bins dwords: [pw][gh*8 + gw4] -> one ds_read_b32 = 4 gw-consecutive bins
    __shared__ unsigned int s_bins[1024];   // 4 KB
    __shared__ float s_vec[120];

    const int tid = threadIdx.x;
    const int bid = blockIdx.x;
    const int b   = bid >> 9;         // 2
    const int gd  = (bid >> 4) & 31;  // 32
    const int pc  = bid & 15;         // p-chunk: p in [pc*4, pc*4+4) -> pd,ph fixed
    const int pd  = pc >> 2, ph = pc & 3;

    if (tid < 120) s_vec[tid] = vectors[tid];

    // ---- Stage 1: one d-plane, one h-phase: voxels (d, 4*gh+ph, all w) ----
    // thread t: row=gh=t>>3, q=t&7 -> loads 64 B (4 float4) at w4 = 4q..4q+3.
    // float4 element j has pw=j, gw=w4 -> pack per-pw dwords (bytes k = gw 4q+k).
    const int row = tid >> 3;   // gh
    const int q   = tid & 7;
    const int d   = (gd << 2) + pd;
    const int h   = (row << 2) + ph;
    const fx4* xr = (const fx4*)(x + ((size_t)b << 21))
                  + (((d << 7) + h) << 5) + (q << 2);
    unsigned int packed[4] = {0u, 0u, 0u, 0u};
    #pragma unroll
    for (int k = 0; k < 4; ++k) {
        const fx4 xv = xr[k];
        #pragma unroll
        for (int j = 0; j < 4; ++j) {
            const float xx = xv[j];
            // searchsorted(side='right') == count(edges <= x)
            unsigned bin = (xx >= -1000.f) + (xx >= -75.f) + (xx >= 0.f)
                         + (xx >= 15.f)   + (xx >= 25.f)  + (xx >= 40.f)
                         + (xx >= 50.f)   + (xx >= 200.f) + (xx >= 1000.f);
            packed[j] |= bin << (k * 8);
        }
    }
    #pragma unroll
    for (int j = 0; j < 4; ++j)
        s_bins[(j << 8) + tid] = packed[j];   // [pw=j][gh*8+gw4 = tid]
    __syncthreads();

    // ---- Stage 2: 48 o-values (o = pc*48 + oo), 4 KB contiguous per o ----
    // thread t covers gh=t>>3, gw=4*(t&7)..+3 -> float4 index within o-slice = t
    fx4* out4 = (fx4*)out
              + ((size_t)((b * 768 + pc * 48) * 32 + gd) << 8) + tid;
    #pragma unroll
    for (int oo = 0; oo < 48; ++oo) {
        const int pw = oo / 12;          // compile-time (full unroll)
        const int v  = oo - pw * 12;
        const unsigned bins = s_bins[(pw << 8) + tid];  // CSEs to 4 regs
        fx4 r;
        r.x = s_vec[(bins & 0xffu) * 12u + v];
        r.y = s_vec[((bins >> 8) & 0xffu) * 12u + v];
        r.z = s_vec[((bins >> 16) & 0xffu) * 12u + v];
        r.w = s_vec[(bins >> 24) * 12u + v];
        __builtin_nontemporal_store(r, out4 + oo * 8192);
    }
}

extern "C" void kernel_launch(void* const* d_in, const int* in_sizes, int n_in,
                              void* d_out, int out_size, void* d_ws, size_t ws_size,
                              hipStream_t stream) {
    const float* x       = (const float*)d_in[0];
    const float* vectors = (const float*)d_in[1];
    float* out           = (float*)d_out;
    lcv_kernel<<<NBLOCKS, NTHREADS, 0, stream>>>(x, vectors, out);
}

// Round 4
// 203.620 us; speedup vs baseline: 1.0563x; 1.0563x over previous
//
#include <hip/hip_runtime.h>

// LearnedClassVectors: bucketize fp32 volume into 10 HU bins, gather (10,12)
// embedding, re-tile into 4x4x4 patches -> out (B=2, 768, 32, 32, 32) fp32.
//
// R3: barrier-free. Block = (b, gd, pc=(pd,ph)). Key identity: stage-1 thread
// t loads x at gw = 4*(t&7)..+3, gh = t>>3 — exactly the (gh,gw) positions
// stage-2 thread t writes. So bins stay in REGISTERS (no s_bins LDS round
// trip, no data barrier). Per channel: 4 ds_read_b32 from the 480 B table
// (v folded into the offset immediate) + 1 contiguous global_store_dwordx4
// (1 KB/wave). x read exactly once; no nt (R2 regression candidate reverted).

#define NTHREADS 256
#define NBLOCKS 1024  // 2 b * 32 gd * 16 p-chunks

typedef float fx4 __attribute__((ext_vector_type(4)));

__global__ __launch_bounds__(NTHREADS) void lcv_kernel(
    const float* __restrict__ x,
    const float* __restrict__ vectors,
    float* __restrict__ out)
{
    __shared__ float s_vec[120];

    const int tid = threadIdx.x;
    const int bid = blockIdx.x;
    const int b   = bid >> 9;         // 2
    const int gd  = (bid >> 4) & 31;  // 32
    const int pc  = bid & 15;         // (pd,ph)
    const int pd  = pc >> 2, ph = pc & 3;

    if (tid < 120) s_vec[tid] = vectors[tid];

    // ---- Load this thread's 16 voxels: (d, h, w = 16q..16q+15) = 4 float4 ----
    const int row = tid >> 3;   // gh
    const int q   = tid & 7;
    const int d   = (gd << 2) + pd;
    const int h   = (row << 2) + ph;
    const fx4* xr = (const fx4*)(x + ((size_t)b << 21))
                  + (((d << 7) + h) << 5) + (q << 2);
    const fx4 xs0 = xr[0], xs1 = xr[1], xs2 = xr[2], xs3 = xr[3];

    __syncthreads();  // s_vec visible (only barrier; no bins round trip)

    // ---- Bins -> table row byte offsets, kept in registers ----
    // float4 k (gw = 4q+k), component j (pw = j): roff[pw][k] = bin*12
    int roff[4][4];
    const fx4 xs[4] = {xs0, xs1, xs2, xs3};
    #pragma unroll
    for (int k = 0; k < 4; ++k) {
        #pragma unroll
        for (int j = 0; j < 4; ++j) {
            const float xx = xs[k][j];
            // searchsorted(side='right') == count(edges <= x)
            const int bin = (xx >= -1000.f) + (xx >= -75.f) + (xx >= 0.f)
                          + (xx >= 15.f)   + (xx >= 25.f)  + (xx >= 40.f)
                          + (xx >= 50.f)   + (xx >= 200.f) + (xx >= 1000.f);
            roff[j][k] = bin * 12;
        }
    }

    // ---- Stream 48 channels: o = pc*48 + pw*12 + v ----
    // thread t = float4 index within the (o, gd) row: 4 KB contiguous per o
    fx4* out4 = (fx4*)out
              + ((size_t)((b * 768 + pc * 48) * 32 + gd) << 8) + tid;
    #pragma unroll
    for (int pw = 0; pw < 4; ++pw) {
        const int r0 = roff[pw][0], r1 = roff[pw][1];
        const int r2 = roff[pw][2], r3 = roff[pw][3];
        #pragma unroll
        for (int v = 0; v < 12; ++v) {
            fx4 r;
            r.x = s_vec[r0 + v];   // ds_read_b32, v*4 in offset imm
            r.y = s_vec[r1 + v];
            r.z = s_vec[r2 + v];
            r.w = s_vec[r3 + v];
            out4[(pw * 12 + v) * 8192] = r;
        }
    }
}

extern "C" void kernel_launch(void* const* d_in, const int* in_sizes, int n_in,
                              void* d_out, int out_size, void* d_ws, size_t ws_size,
                              hipStream_t stream) {
    const float* x       = (const float*)d_in[0];
    const float* vectors = (const float*)d_in[1];
    float* out           = (float*)d_out;
    lcv_kernel<<<NBLOCKS, NTHREADS, 0, stream>>>(x, vectors, out);
}